// Round 4
// baseline (134.278 us; speedup 1.0000x reference)
//
#include <hip/hip_runtime.h>

// loss = sum_i w[i] * sqrt( (0.5*kx+0.5 - rx)^2 + (0.5 - 0.5*ky - ry)^2 )
// z channel / z_norm in the reference is dead code (never feeds loss) —
// but z shares every 64B cache line with x/y (12B/point AoS), so the
// 96 MiB fetch is irreducible. Memory floor: 96 MiB / 6.3 TB/s = 15.2 us.
//
// ROUND 4 = MEASUREMENT PROBE: the main kernel is launched TWICE
// (idempotent partials overwrite -> identical work every call, capture-safe).
// Headline delta vs round 3 (119.3 us) = the main kernel's true duration,
// which never surfaces in the top-5 rocprof rows (all harness fills).

#define TPB 256

__global__ __launch_bounds__(TPB) void viewpoint_partial_kernel(
    const float* __restrict__ kp3d,   // B*N*3 floats, AoS (x,y,z)
    const float* __restrict__ ref,    // B*N*2 floats, AoS (rx,ry)
    const float* __restrict__ w,      // B*N floats
    float* __restrict__ partials)     // one float per block (d_ws)
{
    const float4* kp4 = (const float4*)kp3d;
    const float4* rf4 = (const float4*)ref;
    const float4* w4  = (const float4*)w;

    __shared__ float4 s_kp[TPB * 3];  // 12 KiB
    __shared__ float4 s_rf[TPB * 2];  //  8 KiB

    int t = threadIdx.x;
    size_t blk = blockIdx.x;

    size_t kb = blk * (TPB * 3);
    size_t rb = blk * (TPB * 2);

    float4 wv = w4[blk * TPB + t];           // coalesced

    s_kp[t]            = kp4[kb + t];
    s_kp[TPB + t]      = kp4[kb + TPB + t];
    s_kp[2 * TPB + t]  = kp4[kb + 2 * TPB + t];
    s_rf[t]            = rf4[rb + t];
    s_rf[TPB + t]      = rf4[rb + TPB + t];

    __syncthreads();

    float4 a0 = s_kp[3 * t + 0];   // x0 y0 z0 x1
    float4 a1 = s_kp[3 * t + 1];   // y1 z1 x2 y2
    float4 a2 = s_kp[3 * t + 2];   // z2 x3 y3 z3
    float4 r0 = s_rf[2 * t + 0];   // rx0 ry0 rx1 ry1
    float4 r1 = s_rf[2 * t + 1];   // rx2 ry2 rx3 ry3

    float acc = 0.0f;
    float dx, dy;

    dx = fmaf(a0.x, 0.5f, 0.5f) - r0.x;
    dy = fmaf(a0.y, -0.5f, 0.5f) - r0.y;
    acc += wv.x * sqrtf(fmaf(dx, dx, dy * dy));

    dx = fmaf(a0.w, 0.5f, 0.5f) - r0.z;
    dy = fmaf(a1.x, -0.5f, 0.5f) - r0.w;
    acc += wv.y * sqrtf(fmaf(dx, dx, dy * dy));

    dx = fmaf(a1.z, 0.5f, 0.5f) - r1.x;
    dy = fmaf(a1.w, -0.5f, 0.5f) - r1.y;
    acc += wv.z * sqrtf(fmaf(dx, dx, dy * dy));

    dx = fmaf(a2.y, 0.5f, 0.5f) - r1.z;
    dy = fmaf(a2.z, -0.5f, 0.5f) - r1.w;
    acc += wv.w * sqrtf(fmaf(dx, dx, dy * dy));

    #pragma unroll
    for (int off = 32; off > 0; off >>= 1)
        acc += __shfl_down(acc, off, 64);

    __shared__ float wave_sums[TPB / 64];
    int lane = threadIdx.x & 63;
    int wid  = threadIdx.x >> 6;
    if (lane == 0) wave_sums[wid] = acc;
    __syncthreads();

    if (threadIdx.x == 0) {
        partials[blockIdx.x] = wave_sums[0] + wave_sums[1]
                             + wave_sums[2] + wave_sums[3];
    }
}

__global__ __launch_bounds__(256) void final_reduce_kernel(
    const float* __restrict__ partials, float* __restrict__ out, int n)
{
    float acc = 0.0f;
    for (int i = threadIdx.x; i < n; i += 256)
        acc += partials[i];

    #pragma unroll
    for (int off = 32; off > 0; off >>= 1)
        acc += __shfl_down(acc, off, 64);

    __shared__ float wave_sums[4];
    int lane = threadIdx.x & 63;
    int wid  = threadIdx.x >> 6;
    if (lane == 0) wave_sums[wid] = acc;
    __syncthreads();

    if (threadIdx.x == 0)
        out[0] = wave_sums[0] + wave_sums[1] + wave_sums[2] + wave_sums[3];
}

extern "C" void kernel_launch(void* const* d_in, const int* in_sizes, int n_in,
                              void* d_out, int out_size, void* d_ws, size_t ws_size,
                              hipStream_t stream) {
    const float* kp3d = (const float*)d_in[0];
    const float* ref  = (const float*)d_in[1];
    const float* w    = (const float*)d_in[2];
    float* out = (float*)d_out;
    float* partials = (float*)d_ws;

    int npts = in_sizes[2];             // B*N = 4194304
    int blocks = npts / (TPB * 4);      // 4096

    // PROBE: launch main kernel twice; headline delta vs R3 = its duration.
    viewpoint_partial_kernel<<<blocks, TPB, 0, stream>>>(kp3d, ref, w, partials);
    viewpoint_partial_kernel<<<blocks, TPB, 0, stream>>>(kp3d, ref, w, partials);
    final_reduce_kernel<<<1, 256, 0, stream>>>(partials, out, blocks);
}

// Round 5
// 117.944 us; speedup vs baseline: 1.1385x; 1.1385x over previous
//
#include <hip/hip_runtime.h>

// loss = sum_i w[i] * sqrt( (0.5*kx+0.5 - rx)^2 + (0.5 - 0.5*ky - ry)^2 )
// z channel / z_norm in the reference is dead code (never feeds loss) —
// but z shares every 64B cache line with x/y (12B/point AoS), so the
// 96 MiB (100.7 MB) fetch is irreducible.
//
// ROOFLINE (measured via R4 double-launch probe): main kernel = 14.96 us
// = 100.7 MB / 6.73 TB/s — at/above the 6.5 TB/s ceiling the harness's
// own 256 MiB fills demonstrate (excess = partial L3 residency). The
// remaining ~104 us of headline is fixed harness work (input restore +
// ws/out re-poison), not controllable from kernel_launch.

#define TPB 256

__global__ __launch_bounds__(TPB) void viewpoint_partial_kernel(
    const float* __restrict__ kp3d,   // B*N*3 floats, AoS (x,y,z)
    const float* __restrict__ ref,    // B*N*2 floats, AoS (rx,ry)
    const float* __restrict__ w,      // B*N floats
    float* __restrict__ partials)     // one float per block (d_ws)
{
    const float4* kp4 = (const float4*)kp3d;
    const float4* rf4 = (const float4*)ref;
    const float4* w4  = (const float4*)w;

    __shared__ float4 s_kp[TPB * 3];  // 12 KiB: block's kp3d chunk
    __shared__ float4 s_rf[TPB * 2];  //  8 KiB: block's ref chunk

    int t = threadIdx.x;
    size_t blk = blockIdx.x;

    size_t kb = blk * (TPB * 3);
    size_t rb = blk * (TPB * 2);

    float4 wv = w4[blk * TPB + t];           // lane-contiguous, coalesced

    // Perfectly coalesced global->LDS staging (lane-contiguous float4).
    s_kp[t]            = kp4[kb + t];
    s_kp[TPB + t]      = kp4[kb + TPB + t];
    s_kp[2 * TPB + t]  = kp4[kb + 2 * TPB + t];
    s_rf[t]            = rf4[rb + t];
    s_rf[TPB + t]      = rf4[rb + TPB + t];

    __syncthreads();

    // Per-thread AoS readback from LDS (12-float stride: conflict-free
    // b128 across 32 banks; 8-float stride: 2-way aliasing, free).
    float4 a0 = s_kp[3 * t + 0];   // x0 y0 z0 x1
    float4 a1 = s_kp[3 * t + 1];   // y1 z1 x2 y2
    float4 a2 = s_kp[3 * t + 2];   // z2 x3 y3 z3
    float4 r0 = s_rf[2 * t + 0];   // rx0 ry0 rx1 ry1
    float4 r1 = s_rf[2 * t + 1];   // rx2 ry2 rx3 ry3

    float acc = 0.0f;
    float dx, dy;

    dx = fmaf(a0.x, 0.5f, 0.5f) - r0.x;
    dy = fmaf(a0.y, -0.5f, 0.5f) - r0.y;
    acc += wv.x * sqrtf(fmaf(dx, dx, dy * dy));

    dx = fmaf(a0.w, 0.5f, 0.5f) - r0.z;
    dy = fmaf(a1.x, -0.5f, 0.5f) - r0.w;
    acc += wv.y * sqrtf(fmaf(dx, dx, dy * dy));

    dx = fmaf(a1.z, 0.5f, 0.5f) - r1.x;
    dy = fmaf(a1.w, -0.5f, 0.5f) - r1.y;
    acc += wv.z * sqrtf(fmaf(dx, dx, dy * dy));

    dx = fmaf(a2.y, 0.5f, 0.5f) - r1.z;
    dy = fmaf(a2.z, -0.5f, 0.5f) - r1.w;
    acc += wv.w * sqrtf(fmaf(dx, dx, dy * dy));

    // wave-64 reduction
    #pragma unroll
    for (int off = 32; off > 0; off >>= 1)
        acc += __shfl_down(acc, off, 64);

    __shared__ float wave_sums[TPB / 64];
    int lane = threadIdx.x & 63;
    int wid  = threadIdx.x >> 6;
    if (lane == 0) wave_sums[wid] = acc;
    __syncthreads();

    if (threadIdx.x == 0) {
        partials[blockIdx.x] = wave_sums[0] + wave_sums[1]
                             + wave_sums[2] + wave_sums[3];
    }
}

__global__ __launch_bounds__(256) void final_reduce_kernel(
    const float* __restrict__ partials, float* __restrict__ out, int n)
{
    float acc = 0.0f;
    for (int i = threadIdx.x; i < n; i += 256)
        acc += partials[i];

    #pragma unroll
    for (int off = 32; off > 0; off >>= 1)
        acc += __shfl_down(acc, off, 64);

    __shared__ float wave_sums[4];
    int lane = threadIdx.x & 63;
    int wid  = threadIdx.x >> 6;
    if (lane == 0) wave_sums[wid] = acc;
    __syncthreads();

    if (threadIdx.x == 0)
        out[0] = wave_sums[0] + wave_sums[1] + wave_sums[2] + wave_sums[3];
}

extern "C" void kernel_launch(void* const* d_in, const int* in_sizes, int n_in,
                              void* d_out, int out_size, void* d_ws, size_t ws_size,
                              hipStream_t stream) {
    const float* kp3d = (const float*)d_in[0];
    const float* ref  = (const float*)d_in[1];
    const float* w    = (const float*)d_in[2];
    float* out = (float*)d_out;
    float* partials = (float*)d_ws;

    int npts = in_sizes[2];             // B*N = 4194304
    int blocks = npts / (TPB * 4);      // 4096

    viewpoint_partial_kernel<<<blocks, TPB, 0, stream>>>(kp3d, ref, w, partials);
    final_reduce_kernel<<<1, 256, 0, stream>>>(partials, out, blocks);
}